// Round 4
// baseline (149.837 us; speedup 1.0000x reference)
//
#include <hip/hip_runtime.h>
#include <float.h>
#include <math.h>

#define NSAMPLE 8192
#define KSEL 9          // K+1: keep 9 smallest incl. self
#define KNN 8
#define BLK 512
#define EPS_F 1e-12f

#define ROWS_PB 8                    // rows per block -> 1024 blocks
#define NBLOCKS (NSAMPLE / ROWS_PB)  // 1024
#define RPT 8                        // all 8 rows per thread (octant scan)
#define LANES 64
#define KQT 16                       // scan iters per wave (1024-cand octant / 64)
#define BNDI 4                       // bound iters per wave (256 of the octant)
#define WCAP 32                      // survivor cap per (wave,row) list
#define BP 129                       // bound minima stride (128 + 1 pad)
#define IDX_MASK 0x1FFFu             // low 13 bits = candidate index
#define VAL_MASK 0xFFFFE000u         // high 19 bits = d2 (sign+exp+10 mantissa)
#define PROW 73                      // merge-row stride (72 + 1 pad)
#define SROW 145                     // scratch stride (16*9 + 1)
#define SCALE (1.0f / (float)(NSAMPLE * KNN * 3))

__device__ __forceinline__ unsigned umn(unsigned a, unsigned b) { return a < b ? a : b; }
__device__ __forceinline__ unsigned umx(unsigned a, unsigned b) { return a > b ? a : b; }

// Branchless insert of x into descending-sorted s[0..8] (s[0]=worst, s[8]=best).
__device__ __forceinline__ void insert9(unsigned s[KSEL], unsigned x)
{
#pragma unroll
    for (int k = 0; k < KSEL - 1; ++k)
        s[k] = umx(s[k + 1], umn(x, s[k]));
    s[KSEL - 1] = umn(x, s[KSEL - 1]);
}

// Packed (d2 | idx). d2 clamped >= 0 so self packs minimal.
__device__ __forceinline__ unsigned pack_d2(float d2, int gidx)
{
    return (__float_as_uint(fmaxf(d2, 0.0f)) & VAL_MASK) | (unsigned)gidx;
}

// Force a wave-uniform float into an SGPR (frees per-lane VGPR copies).
__device__ __forceinline__ float sfl(float x)
{
    return __uint_as_float((unsigned)__builtin_amdgcn_readfirstlane(
        (int)__float_as_uint(x)));
}

// popcount(mask & lanes_below_me) in 2 VALU (v_mbcnt_lo/hi).
__device__ __forceinline__ unsigned mbcnt64(unsigned long long m)
{
    return __builtin_amdgcn_mbcnt_hi((unsigned)(m >> 32),
           __builtin_amdgcn_mbcnt_lo((unsigned)(m & 0xFFFFFFFFull), 0u));
}

// ---------------------------------------------------------------------------
// Kernel 1: one-time gather into compact L2-resident float4 arrays:
//   sm4 = (mean.xyz, |mean|^2), ss4 = (sh0.xyz, 0).
// ---------------------------------------------------------------------------
__global__ __launch_bounds__(256) void gather_k(
    const float* __restrict__ means, const float* __restrict__ sh0,
    const int* __restrict__ idx,
    float4* __restrict__ sm4, float4* __restrict__ ss4)
{
    int i = blockIdx.x * 256 + threadIdx.x;
    if (i >= NSAMPLE) return;
    int id = idx[i];
    const float* m = means + 3 * id;
    const float* s = sh0 + 3 * id;
    float mx = m[0], my = m[1], mz = m[2];
    sm4[i] = make_float4(mx, my, mz, fmaf(mx, mx, fmaf(my, my, mz * mz)));
    ss4[i] = make_float4(s[0], s[1], s[2], 0.0f);
}

// ---------------------------------------------------------------------------
// Kernel 2 (R20): identical to R19 except the scan is straight-line with an
// 8-deep named-register candidate pipeline. R19 post-mortem: no spill, no
// HBM, no bank conflicts, occupancy 80%, yet VALUBusy 37% -- SIMDs idle 63%.
// VGPR_Count=28 shows the compiler kept only a depth-2 window (one load in
// flight vs ~112cy compute against 150-250cy L1/L2 latency => per-candidate
// stall, and barrier-lockstepped waves stall together). R20: chunk A (8
// float4, named a0..a7) preloaded; chunk B's loads issue one-per-CAND during
// A's processing (in-flight depth ~8, each load covered by ~900cy compute).
// Buffer ~36 VGPR, est. total ~56; __launch_bounds__(512,8) caps 64 VGPR to
// hold 4 blocks/CU (tripwire: FETCH_SIZE blowup if it spills).
// Screen/packing/dup semantics bit-inherited -> selection exact.
// ---------------------------------------------------------------------------
// Process rows R..R+3 (R = literal 0 or 4) of one candidate register Q.
#define QUAD(R, Q, CI)                                                        \
    {                                                                         \
        float v0 = fmaf(cX[(R) + 0], (Q).x, fmaf(cY[(R) + 0], (Q).y,          \
                   fmaf(cZ[(R) + 0], (Q).z, (Q).w)));                         \
        float v1 = fmaf(cX[(R) + 1], (Q).x, fmaf(cY[(R) + 1], (Q).y,          \
                   fmaf(cZ[(R) + 1], (Q).z, (Q).w)));                         \
        float v2 = fmaf(cX[(R) + 2], (Q).x, fmaf(cY[(R) + 2], (Q).y,          \
                   fmaf(cZ[(R) + 2], (Q).z, (Q).w)));                         \
        float v3 = fmaf(cX[(R) + 3], (Q).x, fmaf(cY[(R) + 3], (Q).y,          \
                   fmaf(cZ[(R) + 3], (Q).z, (Q).w)));                         \
        unsigned long long m0 = __ballot(v0 <= sb[(R) + 0]);                  \
        unsigned long long m1 = __ballot(v1 <= sb[(R) + 1]);                  \
        unsigned long long m2 = __ballot(v2 <= sb[(R) + 2]);                  \
        unsigned long long m3 = __ballot(v3 <= sb[(R) + 3]);                  \
        if (m0) {                                                             \
            unsigned pos = base[(R) + 0] + mbcnt64(m0);                       \
            if ((v0 <= sb[(R) + 0]) && pos < WCAP)                            \
                wl[(w * RPT + (R) + 0) * WCAP + pos] =                        \
                    pack_d2(v0 + cW[(R) + 0], (CI));                          \
            base[(R) + 0] += (unsigned)__popcll(m0);                          \
        }                                                                     \
        if (m1) {                                                             \
            unsigned pos = base[(R) + 1] + mbcnt64(m1);                       \
            if ((v1 <= sb[(R) + 1]) && pos < WCAP)                            \
                wl[(w * RPT + (R) + 1) * WCAP + pos] =                        \
                    pack_d2(v1 + cW[(R) + 1], (CI));                          \
            base[(R) + 1] += (unsigned)__popcll(m1);                          \
        }                                                                     \
        if (m2) {                                                             \
            unsigned pos = base[(R) + 2] + mbcnt64(m2);                       \
            if ((v2 <= sb[(R) + 2]) && pos < WCAP)                            \
                wl[(w * RPT + (R) + 2) * WCAP + pos] =                        \
                    pack_d2(v2 + cW[(R) + 2], (CI));                          \
            base[(R) + 2] += (unsigned)__popcll(m2);                          \
        }                                                                     \
        if (m3) {                                                             \
            unsigned pos = base[(R) + 3] + mbcnt64(m3);                       \
            if ((v3 <= sb[(R) + 3]) && pos < WCAP)                            \
                wl[(w * RPT + (R) + 3) * WCAP + pos] =                        \
                    pack_d2(v3 + cW[(R) + 3], (CI));                          \
            base[(R) + 3] += (unsigned)__popcll(m3);                          \
        }                                                                     \
    }

// One candidate register against all 8 rows.
#define CAND(Q, KI)                                                           \
    {                                                                         \
        const int ci = s0 + (KI) * LANES + lane;                              \
        QUAD(0, Q, ci)                                                        \
        QUAD(4, Q, ci)                                                        \
    }

__global__ __launch_bounds__(BLK, 8) void main_k(
    const float4* __restrict__ sm4, const float4* __restrict__ ss4,
    float* __restrict__ partial)
{
    __shared__ unsigned wl[8 * RPT * WCAP];       // 8 KB private survivor lists
    __shared__ unsigned wcnt[8 * RPT];
    __shared__ unsigned bpart[ROWS_PB * BP];      // 4.1 KB bound minima (folded)
    __shared__ unsigned scratch[ROWS_PB * SROW];  // 4.6 KB bound-merge scratch
    __shared__ unsigned partS[ROWS_PB * PROW];    // 2.3 KB merge scratch 2
    __shared__ unsigned bnd[ROWS_PB];
    __shared__ float    red[ROWS_PB];

    const int t = threadIdx.x;
    const int lane = t & (LANES - 1);
    const int w = t >> 6;                       // 0..7 (wave id = octant)

    // Own-row coefficients -> SGPRs (wave-uniform; canonical d2 = s + cW
    // where s = fmaf(cX,qx, fmaf(cY,qy, fmaf(cZ,qz, qw)))).
    float cX[RPT], cY[RPT], cZ[RPT], cW[RPT];
#pragma unroll
    for (int i = 0; i < RPT; ++i) {
        float4 p = sm4[blockIdx.x * ROWS_PB + i];
        cX[i] = sfl(-2.0f * p.x);
        cY[i] = sfl(-2.0f * p.y);
        cZ[i] = sfl(-2.0f * p.z);
        cW[i] = sfl(p.w);
    }

    // ---- Bound: per-lane packed min over 4-cand slices of the octant's
    // first 256 cands (8 octants -> 2048-cand sample). Fold lanes ^32,^16
    // -> 128 minima/row (each the min of 16 distinct candidates).
    {
        unsigned pm[RPT];
#pragma unroll
        for (int i = 0; i < RPT; ++i) pm[i] = 0xFFFFFFFFu;
        const int b0 = w * (KQT * LANES);
        const float4* __restrict__ bp = sm4 + b0 + lane;
        float4 q0 = bp[0 * LANES];
        float4 q1 = bp[1 * LANES];
        float4 q2 = bp[2 * LANES];
        float4 q3 = bp[3 * LANES];
#pragma unroll
        for (int i = 0; i < RPT; ++i) {
            float s = fmaf(cX[i], q0.x,
                      fmaf(cY[i], q0.y, fmaf(cZ[i], q0.z, q0.w)));
            pm[i] = umn(pm[i], pack_d2(s + cW[i], b0 + 0 * LANES + lane));
        }
#pragma unroll
        for (int i = 0; i < RPT; ++i) {
            float s = fmaf(cX[i], q1.x,
                      fmaf(cY[i], q1.y, fmaf(cZ[i], q1.z, q1.w)));
            pm[i] = umn(pm[i], pack_d2(s + cW[i], b0 + 1 * LANES + lane));
        }
#pragma unroll
        for (int i = 0; i < RPT; ++i) {
            float s = fmaf(cX[i], q2.x,
                      fmaf(cY[i], q2.y, fmaf(cZ[i], q2.z, q2.w)));
            pm[i] = umn(pm[i], pack_d2(s + cW[i], b0 + 2 * LANES + lane));
        }
#pragma unroll
        for (int i = 0; i < RPT; ++i) {
            float s = fmaf(cX[i], q3.x,
                      fmaf(cY[i], q3.y, fmaf(cZ[i], q3.z, q3.w)));
            pm[i] = umn(pm[i], pack_d2(s + cW[i], b0 + 3 * LANES + lane));
        }
#pragma unroll
        for (int i = 0; i < RPT; ++i) {
            pm[i] = umn(pm[i], (unsigned)__shfl_xor((int)pm[i], 32, 64));
            pm[i] = umn(pm[i], (unsigned)__shfl_xor((int)pm[i], 16, 64));
        }
        if (lane < 16) {
#pragma unroll
            for (int i = 0; i < RPT; ++i)
                bpart[i * BP + w * 16 + lane] = pm[i];
        }
    }
    __syncthreads();

    // Merge 128 minima/row -> bnd = 9th smallest (valid upper bound on the
    // row's true 9th: the 9 minima below it are 9 distinct candidates).
    if (t < 128) {                              // stage 1: 8 rows x 16 groups
        const int r1 = t & (ROWS_PB - 1);
        const int g = t >> 3;                   // 0..15
        unsigned s[KSEL];
#pragma unroll
        for (int k = 0; k < KSEL; ++k) s[k] = 0xFFFFFFFFu;
#pragma unroll
        for (int e = 0; e < 8; ++e)
            insert9(s, bpart[r1 * BP + g * 8 + e]);
#pragma unroll
        for (int k = 0; k < KSEL; ++k)
            scratch[r1 * SROW + g * KSEL + k] = s[k];
    }
    __syncthreads();
    if (t < 64) {                               // stage 2: 8 rows x 8 groups
        const int r1 = t & (ROWS_PB - 1);
        const int mg = t >> 3;                  // 0..7
        unsigned m[KSEL];
#pragma unroll
        for (int k = 0; k < KSEL; ++k) m[k] = 0xFFFFFFFFu;
#pragma unroll
        for (int e = 0; e < 2 * KSEL; ++e)
            insert9(m, scratch[r1 * SROW + (2 * mg) * KSEL + e]);
#pragma unroll
        for (int k = 0; k < KSEL; ++k)
            partS[r1 * PROW + mg * KSEL + k] = m[k];
    }
    __syncthreads();
    if (t < ROWS_PB) {                          // stage 3: 72 -> 9th
        unsigned m[KSEL];
#pragma unroll
        for (int k = 0; k < KSEL; ++k) m[k] = 0xFFFFFFFFu;
#pragma unroll
        for (int e = 0; e < 8 * KSEL; ++e)
            insert9(m, partS[t * PROW + e]);
        bnd[t] = m[0];
    }
    __syncthreads();

    // s-space screen bound: pack(d2)|idx <= b requires d2 <= bf where
    // bf = uint_as_float(b | IDX_MASK) (positive floats: uint order == float
    // order). d2 = fl(s + cW) <= bf  ==>  s <= (bf - cW) + ~ulp slack; the
    // relative loosening (on bf AND the difference) keeps sb a superset
    // bound under all cancellation cases. Extras are harmless.
    float sb[RPT];
#pragma unroll
    for (int i = 0; i < RPT; ++i) {
        float bfv = __uint_as_float(bnd[i] | IDX_MASK);
        float D = bfv - cW[i];
        sb[i] = sfl(D + (bfv + fabsf(D)) * 6.0e-7f + 1e-33f);
    }

    // ---- Scan: straight-line, 8-deep named-register candidate pipeline ---
    unsigned base[RPT];
#pragma unroll
    for (int i = 0; i < RPT; ++i) base[i] = 0u;

    const int s0 = w * (KQT * LANES);
    const float4* __restrict__ qp = sm4 + s0 + lane;

    // Chunk A: 8 candidates resident (32 VGPR).
    float4 a0 = qp[0 * LANES], a1 = qp[1 * LANES];
    float4 a2 = qp[2 * LANES], a3 = qp[3 * LANES];
    float4 a4 = qp[4 * LANES], a5 = qp[5 * LANES];
    float4 a6 = qp[6 * LANES], a7 = qp[7 * LANES];

    // Chunk B loads interleaved one-per-CAND: depth ~8 in flight, each load
    // covered by the remaining chunk-A compute (~100cy per CAND).
    float4 b0 = qp[ 8 * LANES];  CAND(a0,  0)
    float4 b1 = qp[ 9 * LANES];  CAND(a1,  1)
    float4 b2 = qp[10 * LANES];  CAND(a2,  2)
    float4 b3 = qp[11 * LANES];  CAND(a3,  3)
    float4 b4 = qp[12 * LANES];  CAND(a4,  4)
    float4 b5 = qp[13 * LANES];  CAND(a5,  5)
    float4 b6 = qp[14 * LANES];  CAND(a6,  6)
    float4 b7 = qp[15 * LANES];  CAND(a7,  7)

    CAND(b0,  8)  CAND(b1,  9)  CAND(b2, 10)  CAND(b3, 11)
    CAND(b4, 12)  CAND(b5, 13)  CAND(b6, 14)  CAND(b7, 15)

    if (lane == 0) {
#pragma unroll
        for (int i = 0; i < RPT; ++i)
            wcnt[w * RPT + i] = umn(base[i], WCAP);
    }
    __syncthreads();                             // survivor lists complete

    // ---- Select: 64 tasks, each merges one (wave,row) list ---------------
    if (t < 64) {
        const int r1 = t & (ROWS_PB - 1);        // row
        const int wv = t >> 3;                   // 0..7 octant wave
        const int li = wv * RPT + r1;
        const unsigned n = wcnt[li];
        unsigned s[KSEL];
#pragma unroll
        for (int k = 0; k < KSEL; ++k) s[k] = 0xFFFFFFFFu;
        for (unsigned k = 0; k < n; ++k)
            insert9(s, wl[li * WCAP + k]);
#pragma unroll
        for (int k = 0; k < KSEL; ++k)
            partS[r1 * PROW + wv * KSEL + k] = s[k];
    }
    __syncthreads();

    if (t < ROWS_PB) {                          // final 72-merge + epilogue
        unsigned m[KSEL];
#pragma unroll
        for (int k = 0; k < KSEL; ++k) m[k] = 0xFFFFFFFFu;
#pragma unroll
        for (int e = 0; e < 8 * KSEL; ++e)
            insert9(m, partS[t * PROW + e]);

        // m[8] = global min (self, or identical-coordinate dup whose term is
        // 0 either way) -> dropped. m[0..7] = the 8 neighbors.
        const int gr = blockIdx.x * ROWS_PB + t;
        float4 pm4 = sm4[gr];
        float4 ps4 = ss4[gr];
        float acc = 0.0f;
#pragma unroll
        for (int k = 0; k < KNN; ++k) {
            int j = (int)(m[k] & IDX_MASK);
            float4 qm = sm4[j];
            float dx = pm4.x - qm.x, dy = pm4.y - qm.y, dz = pm4.z - qm.z;
            float d2 = fmaf(dx, dx, fmaf(dy, dy, dz * dz));
            float d = sqrtf(fmaxf(d2, EPS_F));
            float wgt = expf(-d);
            float4 qs = ss4[j];
            float ax = ps4.x - qs.x, ay = ps4.y - qs.y, az = ps4.z - qs.z;
            acc += wgt * (ax * ax + ay * ay + az * az);
        }
        red[t] = acc;
    }
    __syncthreads();
    if (t == 0) {
        float ssum = 0.0f;
#pragma unroll
        for (int i = 0; i < ROWS_PB; ++i) ssum += red[i];
        partial[blockIdx.x] = ssum;              // plain store
    }
}

// ---------------------------------------------------------------------------
// Kernel 3: reduce 1024 block partials -> scalar (cost ~0, proven R15;
// kept deterministic/order-identical so the output stays bit-exact).
// ---------------------------------------------------------------------------
__global__ __launch_bounds__(256) void reduce_k(
    const float* __restrict__ partial, float* __restrict__ out)
{
    __shared__ float sbuf[4];
    int t = threadIdx.x;
    float v = 0.0f;
    for (int i = t; i < NBLOCKS; i += 256) v += partial[i];
    for (int off = 32; off > 0; off >>= 1) v += __shfl_down(v, off);
    if ((t & 63) == 0) sbuf[t >> 6] = v;
    __syncthreads();
    if (t == 0) {
        float s = sbuf[0] + sbuf[1] + sbuf[2] + sbuf[3];
        out[0] = s * SCALE;
    }
}

// ---------------------------------------------------------------------------
extern "C" void kernel_launch(void* const* d_in, const int* in_sizes, int n_in,
                              void* d_out, int out_size, void* d_ws, size_t ws_size,
                              hipStream_t stream)
{
    const float* means = (const float*)d_in[0];
    const float* sh0   = (const float*)d_in[1];
    const int*   idxp  = (const int*)d_in[2];

    float4* sm4 = (float4*)d_ws;                 // 128 KB
    float4* ss4 = sm4 + NSAMPLE;                 // 128 KB
    float*  partial = (float*)(ss4 + NSAMPLE);   // 4 KB

    gather_k<<<NSAMPLE / 256, 256, 0, stream>>>(means, sh0, idxp, sm4, ss4);
    main_k<<<NBLOCKS, BLK, 0, stream>>>(sm4, ss4, partial);
    reduce_k<<<1, 256, 0, stream>>>(partial, (float*)d_out);
}

// Round 5
// 107.696 us; speedup vs baseline: 1.3913x; 1.3913x over previous
//
#include <hip/hip_runtime.h>
#include <float.h>
#include <math.h>

#define NSAMPLE 8192
#define KSEL 9          // K+1: keep 9 smallest incl. self
#define KNN 8
#define BLK 512
#define EPS_F 1e-12f

#define ROWS_PB 8                    // rows per block -> 1024 blocks
#define NBLOCKS (NSAMPLE / ROWS_PB)  // 1024
#define RPT 8                        // all 8 rows per thread (octant scan)
#define LANES 64
#define KQT 16                       // scan iters per wave (1024-cand octant / 64)
#define BNDI 4                       // bound iters per wave (256 of the octant)
#define WCAP 32                      // survivor cap per (wave,row) list
#define BP 129                       // bound minima stride (128 + 1 pad)
#define IDX_MASK 0x1FFFu             // low 13 bits = candidate index
#define VAL_MASK 0xFFFFE000u         // high 19 bits = d2 (sign+exp+10 mantissa)
#define PROW 73                      // merge-row stride (72 + 1 pad)
#define SROW 145                     // scratch stride (16*9 + 1)
#define SCALE (1.0f / (float)(NSAMPLE * KNN * 3))

__device__ __forceinline__ unsigned umn(unsigned a, unsigned b) { return a < b ? a : b; }
__device__ __forceinline__ unsigned umx(unsigned a, unsigned b) { return a > b ? a : b; }

// Branchless insert of x into descending-sorted s[0..8] (s[0]=worst, s[8]=best).
__device__ __forceinline__ void insert9(unsigned s[KSEL], unsigned x)
{
#pragma unroll
    for (int k = 0; k < KSEL - 1; ++k)
        s[k] = umx(s[k + 1], umn(x, s[k]));
    s[KSEL - 1] = umn(x, s[KSEL - 1]);
}

// Packed (d2 | idx). d2 clamped >= 0 so self packs minimal.
__device__ __forceinline__ unsigned pack_d2(float d2, int gidx)
{
    return (__float_as_uint(fmaxf(d2, 0.0f)) & VAL_MASK) | (unsigned)gidx;
}

// Force a wave-uniform float into an SGPR (frees per-lane VGPR copies).
__device__ __forceinline__ float sfl(float x)
{
    return __uint_as_float((unsigned)__builtin_amdgcn_readfirstlane(
        (int)__float_as_uint(x)));
}

// popcount(mask & lanes_below_me) in 2 VALU (v_mbcnt_lo/hi).
__device__ __forceinline__ unsigned mbcnt64(unsigned long long m)
{
    return __builtin_amdgcn_mbcnt_hi((unsigned)(m >> 32),
           __builtin_amdgcn_mbcnt_lo((unsigned)(m & 0xFFFFFFFFull), 0u));
}

// ---------------------------------------------------------------------------
// Kernel 1: one-time gather into compact L2-resident float4 arrays:
//   sm4 = (mean.xyz, |mean|^2), ss4 = (sh0.xyz, 0).
// ---------------------------------------------------------------------------
__global__ __launch_bounds__(256) void gather_k(
    const float* __restrict__ means, const float* __restrict__ sh0,
    const int* __restrict__ idx,
    float4* __restrict__ sm4, float4* __restrict__ ss4)
{
    int i = blockIdx.x * 256 + threadIdx.x;
    if (i >= NSAMPLE) return;
    int id = idx[i];
    const float* m = means + 3 * id;
    const float* s = sh0 + 3 * id;
    float mx = m[0], my = m[1], mz = m[2];
    sm4[i] = make_float4(mx, my, mz, fmaf(mx, mx, fmaf(my, my, mz * mz)));
    ss4[i] = make_float4(s[0], s[1], s[2], 0.0f);
}

// ---------------------------------------------------------------------------
// Kernel 2 (R21): R19 structure (verified correct: no spill, occupancy 80%)
// with the scan's load pipeline deepened WITHIN budget. Post-mortems:
//   R19: depth-2 window -> VALUBusy 37%, SIMDs idle on vmcnt (46us).
//   R20: depth-16 (64 buffer VGPR, all live at once) under a 64-VGPR cap
//        -> spill catastrophe (FETCH 47MB, 80us). Depth is the lever but
//        must fit the register budget at the occupancy target.
// R21: __launch_bounds__(512,5) (cap ~100 VGPR) + straight-line scan with
// INTERLEAVED load/consume (load c[k+6]; process c[k]): peak liveness
// 7 float4 = 28 buffer VGPR (est. total ~60 -> still 8 waves/SIMD; LDS
// 19.5KB -> 4 blocks/CU -> full occupancy KEPT). Effective prefetch
// distance 6 cands ~ 840cy compute per load >> 300cy L2 latency.
// Tripwire: FETCH_SIZE must stay ~1.2MB; blowup = spill = revert depth.
// Screen/packing/dup semantics bit-inherited from R19 -> selection exact.
// ---------------------------------------------------------------------------
// Process rows R..R+3 (R = literal 0 or 4) of one candidate register Q.
#define QUAD(R, Q, CI)                                                        \
    {                                                                         \
        float v0 = fmaf(cX[(R) + 0], (Q).x, fmaf(cY[(R) + 0], (Q).y,          \
                   fmaf(cZ[(R) + 0], (Q).z, (Q).w)));                         \
        float v1 = fmaf(cX[(R) + 1], (Q).x, fmaf(cY[(R) + 1], (Q).y,          \
                   fmaf(cZ[(R) + 1], (Q).z, (Q).w)));                         \
        float v2 = fmaf(cX[(R) + 2], (Q).x, fmaf(cY[(R) + 2], (Q).y,          \
                   fmaf(cZ[(R) + 2], (Q).z, (Q).w)));                         \
        float v3 = fmaf(cX[(R) + 3], (Q).x, fmaf(cY[(R) + 3], (Q).y,          \
                   fmaf(cZ[(R) + 3], (Q).z, (Q).w)));                         \
        unsigned long long m0 = __ballot(v0 <= sb[(R) + 0]);                  \
        unsigned long long m1 = __ballot(v1 <= sb[(R) + 1]);                  \
        unsigned long long m2 = __ballot(v2 <= sb[(R) + 2]);                  \
        unsigned long long m3 = __ballot(v3 <= sb[(R) + 3]);                  \
        if (m0) {                                                             \
            unsigned pos = base[(R) + 0] + mbcnt64(m0);                       \
            if ((v0 <= sb[(R) + 0]) && pos < WCAP)                            \
                wl[(w * RPT + (R) + 0) * WCAP + pos] =                        \
                    pack_d2(v0 + cW[(R) + 0], (CI));                          \
            base[(R) + 0] += (unsigned)__popcll(m0);                          \
        }                                                                     \
        if (m1) {                                                             \
            unsigned pos = base[(R) + 1] + mbcnt64(m1);                       \
            if ((v1 <= sb[(R) + 1]) && pos < WCAP)                            \
                wl[(w * RPT + (R) + 1) * WCAP + pos] =                        \
                    pack_d2(v1 + cW[(R) + 1], (CI));                          \
            base[(R) + 1] += (unsigned)__popcll(m1);                          \
        }                                                                     \
        if (m2) {                                                             \
            unsigned pos = base[(R) + 2] + mbcnt64(m2);                       \
            if ((v2 <= sb[(R) + 2]) && pos < WCAP)                            \
                wl[(w * RPT + (R) + 2) * WCAP + pos] =                        \
                    pack_d2(v2 + cW[(R) + 2], (CI));                          \
            base[(R) + 2] += (unsigned)__popcll(m2);                          \
        }                                                                     \
        if (m3) {                                                             \
            unsigned pos = base[(R) + 3] + mbcnt64(m3);                       \
            if ((v3 <= sb[(R) + 3]) && pos < WCAP)                            \
                wl[(w * RPT + (R) + 3) * WCAP + pos] =                        \
                    pack_d2(v3 + cW[(R) + 3], (CI));                          \
            base[(R) + 3] += (unsigned)__popcll(m3);                          \
        }                                                                     \
    }

// One candidate register against all 8 rows.
#define CAND(Q, KI)                                                           \
    {                                                                         \
        const int ci = s0 + (KI) * LANES + lane;                              \
        QUAD(0, Q, ci)                                                        \
        QUAD(4, Q, ci)                                                        \
    }

__global__ __launch_bounds__(BLK, 5) void main_k(
    const float4* __restrict__ sm4, const float4* __restrict__ ss4,
    float* __restrict__ partial)
{
    __shared__ unsigned wl[8 * RPT * WCAP];       // 8 KB private survivor lists
    __shared__ unsigned wcnt[8 * RPT];
    __shared__ unsigned bpart[ROWS_PB * BP];      // 4.1 KB bound minima (folded)
    __shared__ unsigned scratch[ROWS_PB * SROW];  // 4.6 KB bound-merge scratch
    __shared__ unsigned partS[ROWS_PB * PROW];    // 2.3 KB merge scratch 2
    __shared__ unsigned bnd[ROWS_PB];
    __shared__ float    red[ROWS_PB];

    const int t = threadIdx.x;
    const int lane = t & (LANES - 1);
    const int w = t >> 6;                       // 0..7 (wave id = octant)

    // Own-row coefficients -> SGPRs (wave-uniform; canonical d2 = s + cW
    // where s = fmaf(cX,qx, fmaf(cY,qy, fmaf(cZ,qz, qw)))).
    float cX[RPT], cY[RPT], cZ[RPT], cW[RPT];
#pragma unroll
    for (int i = 0; i < RPT; ++i) {
        float4 p = sm4[blockIdx.x * ROWS_PB + i];
        cX[i] = sfl(-2.0f * p.x);
        cY[i] = sfl(-2.0f * p.y);
        cZ[i] = sfl(-2.0f * p.z);
        cW[i] = sfl(p.w);
    }

    // ---- Bound: per-lane packed min over 4-cand slices of the octant's
    // first 256 cands (8 octants -> 2048-cand sample). Fold lanes ^32,^16
    // -> 128 minima/row (each the min of 16 distinct candidates).
    {
        unsigned pm[RPT];
#pragma unroll
        for (int i = 0; i < RPT; ++i) pm[i] = 0xFFFFFFFFu;
        const int b0 = w * (KQT * LANES);
        const float4* __restrict__ bp = sm4 + b0 + lane;
        float4 q0 = bp[0 * LANES];
        float4 q1 = bp[1 * LANES];
        float4 q2 = bp[2 * LANES];
        float4 q3 = bp[3 * LANES];
#pragma unroll
        for (int i = 0; i < RPT; ++i) {
            float s = fmaf(cX[i], q0.x,
                      fmaf(cY[i], q0.y, fmaf(cZ[i], q0.z, q0.w)));
            pm[i] = umn(pm[i], pack_d2(s + cW[i], b0 + 0 * LANES + lane));
        }
#pragma unroll
        for (int i = 0; i < RPT; ++i) {
            float s = fmaf(cX[i], q1.x,
                      fmaf(cY[i], q1.y, fmaf(cZ[i], q1.z, q1.w)));
            pm[i] = umn(pm[i], pack_d2(s + cW[i], b0 + 1 * LANES + lane));
        }
#pragma unroll
        for (int i = 0; i < RPT; ++i) {
            float s = fmaf(cX[i], q2.x,
                      fmaf(cY[i], q2.y, fmaf(cZ[i], q2.z, q2.w)));
            pm[i] = umn(pm[i], pack_d2(s + cW[i], b0 + 2 * LANES + lane));
        }
#pragma unroll
        for (int i = 0; i < RPT; ++i) {
            float s = fmaf(cX[i], q3.x,
                      fmaf(cY[i], q3.y, fmaf(cZ[i], q3.z, q3.w)));
            pm[i] = umn(pm[i], pack_d2(s + cW[i], b0 + 3 * LANES + lane));
        }
#pragma unroll
        for (int i = 0; i < RPT; ++i) {
            pm[i] = umn(pm[i], (unsigned)__shfl_xor((int)pm[i], 32, 64));
            pm[i] = umn(pm[i], (unsigned)__shfl_xor((int)pm[i], 16, 64));
        }
        if (lane < 16) {
#pragma unroll
            for (int i = 0; i < RPT; ++i)
                bpart[i * BP + w * 16 + lane] = pm[i];
        }
    }
    __syncthreads();

    // Merge 128 minima/row -> bnd = 9th smallest (valid upper bound on the
    // row's true 9th: the 9 minima below it are 9 distinct candidates).
    if (t < 128) {                              // stage 1: 8 rows x 16 groups
        const int r1 = t & (ROWS_PB - 1);
        const int g = t >> 3;                   // 0..15
        unsigned s[KSEL];
#pragma unroll
        for (int k = 0; k < KSEL; ++k) s[k] = 0xFFFFFFFFu;
#pragma unroll
        for (int e = 0; e < 8; ++e)
            insert9(s, bpart[r1 * BP + g * 8 + e]);
#pragma unroll
        for (int k = 0; k < KSEL; ++k)
            scratch[r1 * SROW + g * KSEL + k] = s[k];
    }
    __syncthreads();
    if (t < 64) {                               // stage 2: 8 rows x 8 groups
        const int r1 = t & (ROWS_PB - 1);
        const int mg = t >> 3;                  // 0..7
        unsigned m[KSEL];
#pragma unroll
        for (int k = 0; k < KSEL; ++k) m[k] = 0xFFFFFFFFu;
#pragma unroll
        for (int e = 0; e < 2 * KSEL; ++e)
            insert9(m, scratch[r1 * SROW + (2 * mg) * KSEL + e]);
#pragma unroll
        for (int k = 0; k < KSEL; ++k)
            partS[r1 * PROW + mg * KSEL + k] = m[k];
    }
    __syncthreads();
    if (t < ROWS_PB) {                          // stage 3: 72 -> 9th
        unsigned m[KSEL];
#pragma unroll
        for (int k = 0; k < KSEL; ++k) m[k] = 0xFFFFFFFFu;
#pragma unroll
        for (int e = 0; e < 8 * KSEL; ++e)
            insert9(m, partS[t * PROW + e]);
        bnd[t] = m[0];
    }
    __syncthreads();

    // s-space screen bound: pack(d2)|idx <= b requires d2 <= bf where
    // bf = uint_as_float(b | IDX_MASK) (positive floats: uint order == float
    // order). d2 = fl(s + cW) <= bf  ==>  s <= (bf - cW) + ~ulp slack; the
    // relative loosening (on bf AND the difference) keeps sb a superset
    // bound under all cancellation cases. Extras are harmless.
    float sb[RPT];
#pragma unroll
    for (int i = 0; i < RPT; ++i) {
        float bfv = __uint_as_float(bnd[i] | IDX_MASK);
        float D = bfv - cW[i];
        sb[i] = sfl(D + (bfv + fabsf(D)) * 6.0e-7f + 1e-33f);
    }

    // ---- Scan: straight-line, interleaved load/consume, depth-6 ----------
    // Load c[k+6]; process c[k]. Peak float4 liveness = 7 (28 VGPR), so the
    // allocator keeps everything in registers under the ~100-VGPR cap while
    // each load has ~6 candidates (~840cy) of compute to hide under.
    unsigned base[RPT];
#pragma unroll
    for (int i = 0; i < RPT; ++i) base[i] = 0u;

    const int s0 = w * (KQT * LANES);
    const float4* __restrict__ qp = sm4 + s0 + lane;

    float4 c0 = qp[0 * LANES], c1 = qp[1 * LANES], c2 = qp[2 * LANES];
    float4 c3 = qp[3 * LANES], c4 = qp[4 * LANES], c5 = qp[5 * LANES];

    float4 c6  = qp[ 6 * LANES];  CAND(c0,  0)
    float4 c7  = qp[ 7 * LANES];  CAND(c1,  1)
    float4 c8  = qp[ 8 * LANES];  CAND(c2,  2)
    float4 c9  = qp[ 9 * LANES];  CAND(c3,  3)
    float4 c10 = qp[10 * LANES];  CAND(c4,  4)
    float4 c11 = qp[11 * LANES];  CAND(c5,  5)
    float4 c12 = qp[12 * LANES];  CAND(c6,  6)
    float4 c13 = qp[13 * LANES];  CAND(c7,  7)
    float4 c14 = qp[14 * LANES];  CAND(c8,  8)
    float4 c15 = qp[15 * LANES];  CAND(c9,  9)
    CAND(c10, 10)  CAND(c11, 11)  CAND(c12, 12)
    CAND(c13, 13)  CAND(c14, 14)  CAND(c15, 15)

    if (lane == 0) {
#pragma unroll
        for (int i = 0; i < RPT; ++i)
            wcnt[w * RPT + i] = umn(base[i], WCAP);
    }
    __syncthreads();                             // survivor lists complete

    // ---- Select: 64 tasks, each merges one (wave,row) list ---------------
    if (t < 64) {
        const int r1 = t & (ROWS_PB - 1);        // row
        const int wv = t >> 3;                   // 0..7 octant wave
        const int li = wv * RPT + r1;
        const unsigned n = wcnt[li];
        unsigned s[KSEL];
#pragma unroll
        for (int k = 0; k < KSEL; ++k) s[k] = 0xFFFFFFFFu;
        for (unsigned k = 0; k < n; ++k)
            insert9(s, wl[li * WCAP + k]);
#pragma unroll
        for (int k = 0; k < KSEL; ++k)
            partS[r1 * PROW + wv * KSEL + k] = s[k];
    }
    __syncthreads();

    if (t < ROWS_PB) {                          // final 72-merge + epilogue
        unsigned m[KSEL];
#pragma unroll
        for (int k = 0; k < KSEL; ++k) m[k] = 0xFFFFFFFFu;
#pragma unroll
        for (int e = 0; e < 8 * KSEL; ++e)
            insert9(m, partS[t * PROW + e]);

        // m[8] = global min (self, or identical-coordinate dup whose term is
        // 0 either way) -> dropped. m[0..7] = the 8 neighbors.
        const int gr = blockIdx.x * ROWS_PB + t;
        float4 pm4 = sm4[gr];
        float4 ps4 = ss4[gr];
        float acc = 0.0f;
#pragma unroll
        for (int k = 0; k < KNN; ++k) {
            int j = (int)(m[k] & IDX_MASK);
            float4 qm = sm4[j];
            float dx = pm4.x - qm.x, dy = pm4.y - qm.y, dz = pm4.z - qm.z;
            float d2 = fmaf(dx, dx, fmaf(dy, dy, dz * dz));
            float d = sqrtf(fmaxf(d2, EPS_F));
            float wgt = expf(-d);
            float4 qs = ss4[j];
            float ax = ps4.x - qs.x, ay = ps4.y - qs.y, az = ps4.z - qs.z;
            acc += wgt * (ax * ax + ay * ay + az * az);
        }
        red[t] = acc;
    }
    __syncthreads();
    if (t == 0) {
        float ssum = 0.0f;
#pragma unroll
        for (int i = 0; i < ROWS_PB; ++i) ssum += red[i];
        partial[blockIdx.x] = ssum;              // plain store
    }
}

// ---------------------------------------------------------------------------
// Kernel 3: reduce 1024 block partials -> scalar (cost ~0, proven R15;
// kept deterministic/order-identical so the output stays bit-exact).
// ---------------------------------------------------------------------------
__global__ __launch_bounds__(256) void reduce_k(
    const float* __restrict__ partial, float* __restrict__ out)
{
    __shared__ float sbuf[4];
    int t = threadIdx.x;
    float v = 0.0f;
    for (int i = t; i < NBLOCKS; i += 256) v += partial[i];
    for (int off = 32; off > 0; off >>= 1) v += __shfl_down(v, off);
    if ((t & 63) == 0) sbuf[t >> 6] = v;
    __syncthreads();
    if (t == 0) {
        float s = sbuf[0] + sbuf[1] + sbuf[2] + sbuf[3];
        out[0] = s * SCALE;
    }
}

// ---------------------------------------------------------------------------
extern "C" void kernel_launch(void* const* d_in, const int* in_sizes, int n_in,
                              void* d_out, int out_size, void* d_ws, size_t ws_size,
                              hipStream_t stream)
{
    const float* means = (const float*)d_in[0];
    const float* sh0   = (const float*)d_in[1];
    const int*   idxp  = (const int*)d_in[2];

    float4* sm4 = (float4*)d_ws;                 // 128 KB
    float4* ss4 = sm4 + NSAMPLE;                 // 128 KB
    float*  partial = (float*)(ss4 + NSAMPLE);   // 4 KB

    gather_k<<<NSAMPLE / 256, 256, 0, stream>>>(means, sh0, idxp, sm4, ss4);
    main_k<<<NBLOCKS, BLK, 0, stream>>>(sm4, ss4, partial);
    reduce_k<<<1, 256, 0, stream>>>(partial, (float*)d_out);
}